// Round 9
// baseline (501.940 us; speedup 1.0000x reference)
//
#include <hip/hip_runtime.h>

typedef unsigned short u16;
typedef unsigned int   u32;
typedef _Float16 f16x8 __attribute__((ext_vector_type(8)));
typedef float  f32x2  __attribute__((ext_vector_type(2)));
typedef float  f32x4  __attribute__((ext_vector_type(4)));
typedef int    i32x4  __attribute__((ext_vector_type(4)));
typedef u32    u32x2  __attribute__((ext_vector_type(2)));

#define Bn 8
#define Sn 96
#define Tn 96
#define Hn 64
#define H2n 128
#define STRB 152           // state row stride BYTES (128 used): conflict-free, 8B-aligned
#define ARRB 16384         // padded array stride -> scalar parity fold
#define STATEB 131072      // 8 state arrays (2dep x 2stream x 2parity)
#define PXROW 152          // px row stride bytes (128 used)
#define PXG   (Sn*PXROW)   // 14592
#define PXBASE STATEB
#define LDSB  (STATEB + 2*PXG)   // 160256 <= 163840
#define ODS 24320          // 95*Hn*4 : out byte stride per cell along a diagonal
#define TSTP 2432          // 16*STRB == 16*PXROW : byte step per 16-cell tile

__device__ __forceinline__ int imax(int a, int b){ return a > b ? a : b; }
__device__ __forceinline__ int imin(int a, int b){ return a < b ? a : b; }

__device__ __forceinline__ u32 pack2f16(float a, float b){
  _Float16 ha = (_Float16)a, hb = (_Float16)b;    // v_cvt_f16_f32 (RNE)
  return (u32)__builtin_bit_cast(u16, ha) | ((u32)__builtin_bit_cast(u16, hb) << 16);
}
__device__ __forceinline__ float f16tof(u32 v){
  return (float)__builtin_bit_cast(_Float16, (u16)v);
}
// tanh(x) = 1 - 2/(e^{2x}+1); exp2 over/underflow saturates correctly -> no clamp.
__device__ __forceinline__ float fast_tanh(float x){
  float e = exp2f(x * 2.88539008f);
  return __builtin_fmaf(-2.f, __builtin_amdgcn_rcpf(e + 1.f), 1.f);
}
// Workgroup barrier WITHOUT the vmcnt(0) drain __syncthreads() emits:
// only LDS ordering is needed between rounds (out is write-only, never read).
__device__ __forceinline__ void barrier_lds_only(){
  asm volatile("s_waitcnt vmcnt(63) expcnt(7) lgkmcnt(0)\n\ts_barrier" ::: "memory");
}
// state fragment: 8 f16 (16B) as two b64 reads (8B-aligned at STRB=152).
// NEVER use a b128 load here: at stride 152 it is misaligned for odd lanes
// and HW splits it on the dependency chain (R6: 3x regression).
__device__ __forceinline__ f16x8 ld_state(const char* p){
  u32x2 a = *(const u32x2*)(p);
  u32x2 b = *(const u32x2*)(p + 8);
  i32x4 v; v[0] = (int)a[0]; v[1] = (int)a[1]; v[2] = (int)b[0]; v[3] = (int)b[1];
  return __builtin_bit_cast(f16x8, v);
}

// Prologue: depth-0 input projections + bias, px[b,g,row,n] (fp32) into ws.
__global__ __launch_bounds__(64) void proj0_kernel(
  const float* __restrict__ src, const float* __restrict__ trg,
  const float* __restrict__ Wix, const float* __restrict__ Wiy,
  const float* __restrict__ bx, const float* __restrict__ by,
  float* __restrict__ ws)
{
  const int row = blockIdx.x, g = blockIdx.y, b = blockIdx.z;
  const int n = threadIdx.x;
  const float* x = (g == 0) ? (src + (b*Sn + row)*Hn) : (trg + (b*Tn + row)*Hn);
  const float* W = (g == 0) ? Wix : Wiy;
  float a = (g == 0) ? bx[n] : by[n];
  #pragma unroll 8
  for (int f = 0; f < Hn; ++f) a = fmaf(x[f], W[f*Hn + n], a);
  ws[((size_t)(b*2 + g)*Sn + row)*Hn + n] = a;
}

// Fused lag-1 wavefront, 1024 threads = 16 waves: wave = (g, ch, nh, dep).
// R8 structure (32 feats/wave sharing B-frags, halved LDS redundancy) +
// R9: depth-1 SOFTWARE PIPELINE across the 3 cell tiles. R8's counters
// showed pipe costs SUMMING (LDS 2400 + VALU 2100 + MFMA 550 ~= 5150cy
// round): barrier-synced symmetric waves convoy through load->MFMA->tanh
// phases. Manual unroll LOAD(t0) LOAD(t1) COMPUTE(t0) LOAD(t2) COMPUTE(t1)
// COMPUTE(t2) with 2 register staging slots overlaps each tile's ds_reads
// with the previous tile's MFMA/tanh. pv (P-projection) reads stay in the
// compute phase (4 MFMAs ahead hide their latency).
// 16x16x32 MFMA; direct scattered out stores (absorbed by vmcnt(63), never
// on the round chain); single barrier per round; parity-double-buffered
// fp16 state at STRB=152 (conflict-free, 8B-aligned paired-b64 reads).
// Valid-region only (rounds = sl+tl, diagonals clipped); invalid region
// pre-zeroed by memset. Clamped dead lanes read in-bounds finite LDS;
// their columns are never stored.
__global__ __launch_bounds__(1024, 1) void grid_rnn_fused(
  const float* __restrict__ Whx, const float* __restrict__ Why,
  const float* __restrict__ Wix, const float* __restrict__ Wiy,
  const float* __restrict__ bx,  const float* __restrict__ by,
  const int* __restrict__ src_lens, const int* __restrict__ trg_lens,
  float* __restrict__ out, const float* __restrict__ ws)
{
  extern __shared__ u16 smem[];
  char* const smemc = (char*)smem;
  const int b    = blockIdx.x;
  const int tid  = threadIdx.x;
  const int lane = tid & 63;
  const int wid  = __builtin_amdgcn_readfirstlane(tid >> 6);
  const int q    = lane >> 4;
  const int c    = lane & 15;
  const int dep  = wid & 1;
  const int nh   = (wid >> 1) & 1;   // feature half (32 feats)
  const int ch   = (wid >> 2) & 1;   // cell-tile parity
  const int g    = wid >> 3;
  const int sl = __builtin_amdgcn_readfirstlane(src_lens[b]);
  const int tl = __builtin_amdgcn_readfirstlane(trg_lens[b]);
  const int NB = sl + tl;

  for (int idx = tid; idx < STATEB/16; idx += 1024) ((i32x4*)smem)[idx] = (i32x4)(0);

  // stage px: ws fp32 -> LDS fp16 (row stride 152B)
  {
    const int gp = tid >> 9;          // 0/1 stream
    const int t5 = tid & 511;
    const float* wsg = ws + (size_t)(b*2 + gp)*Sn*Hn;
    #pragma unroll
    for (int it = 0; it < 6; ++it){
      int w = t5 + it*512;            // pair index 0..3071
      int row = w >> 5, pr = w & 31;
      f32x2 v = *(const f32x2*)(wsg + row*64 + pr*2);
      *(u32*)(smemc + PXBASE + gp*PXG + row*PXROW + pr*4) = pack2f16(v[0], v[1]);
    }
  }

  // ---- weights (own depth, own 32-feature half = 2 chunks), fp16 A-frags
  const float* Wh = (g == 0 ? Whx : Why) + dep*H2n*Hn;
  i32x4 whf[4][2];
  #pragma unroll
  for (int kk = 0; kk < 4; ++kk)
    #pragma unroll
    for (int fc = 0; fc < 2; ++fc){
      const int nb = nh*32 + fc*16 + c;
      #pragma unroll
      for (int p = 0; p < 4; ++p){
        float w0 = Wh[(kk*32 + q*8 + 2*p    )*Hn + nb];
        float w1 = Wh[(kk*32 + q*8 + 2*p + 1)*Hn + nb];
        whf[kk][fc][p] = (int)pack2f16(w0, w1);
      }
    }
  const float* Wi = (g == 0 ? Wix : Wiy) + Hn*Hn;  // depth-1 slice (dep1 only)
  i32x4 wif[2][2];
  #pragma unroll
  for (int kk = 0; kk < 2; ++kk)
    #pragma unroll
    for (int fc = 0; fc < 2; ++fc){
      const int nb = nh*32 + fc*16 + c;
      #pragma unroll
      for (int p = 0; p < 4; ++p){
        float w0 = Wi[(kk*32 + q*8 + 2*p    )*Hn + nb];
        float w1 = Wi[(kk*32 + q*8 + 2*p + 1)*Hn + nb];
        wif[kk][fc][p] = (int)pack2f16(w0, w1);
      }
    }
  f32x4 bias4[2];  // depth-1 bias (dep0 gets bias via ws projections)
  {
    const float* bb = (g == 0 ? bx : by) + dep*Hn;
    #pragma unroll
    for (int fc = 0; fc < 2; ++fc)
      #pragma unroll
      for (int r4 = 0; r4 < 4; ++r4) bias4[fc][r4] = bb[nh*32 + fc*16 + q*4 + r4];
  }
  char* const outb = (char*)(out + (size_t)((g*2 + dep)*Bn + b)*(size_t)(Sn*Tn)*Hn);

  // per-lane address parts (bytes)
  const int plX  = q*16 - c*STRB;                   // X reads: row j decreasing
  const int plY  = q*16 + c*STRB;                   // Y reads: row i increasing
  const int plP  = g ? plY : plX;
  const int plW  = (g ? c*STRB : -c*STRB) + nh*64 + q*8;   // fc1 at +32
  const int plPx = (g ? -c*PXROW : c*PXROW) + nh*64 + q*8; // fc1 at +32
  const int plO  = c*ODS + nh*128 + q*16;                  // fc1 at +64

  const int depB   = dep*4*ARRB;                    // [X p0][X p1][Y p0][Y p1]
  const int basePg = g ? 2*ARRB : 0;                // dep0's X / Y pair
  const int baseWg = depB + (g ? 2*ARRB : 0);

  __syncthreads();   // init + staging visible

  for (int r = 0; r < NB; ++r){
    const int myd  = r - dep;
    const bool wact = (myd >= 0) && (myd <= NB - 2);
    const int cpB = (r & 1) ? ARRB : 0;
    const int ppB = ARRB - cpB;
    const int i0 = imax(0, myd - (tl - 1));
    const int i1 = imin(sl - 1, myd);
    const int nc = i1 - i0 + 1;
    const int mtiles = (nc + 15) >> 4;
    const int rJ0 = myd - i0, rJm = myd - i1;
    const int aX  = depB + ppB + rJ0*STRB;
    const int loX = depB + ppB + rJm*STRB;
    const int aY  = depB + 2*ARRB + ppB + i0*STRB;
    const int hiY = depB + 2*ARRB + ppB + i1*STRB + 48;
    const int aP  = basePg + ppB + (g ? i0 : rJ0)*STRB;
    const int loP = basePg + ppB + (g ? i0 : rJm)*STRB;
    const int hiP = basePg + ppB + (g ? i1 : rJ0)*STRB + 48;
    const int aW  = baseWg + cpB + (g ? i0 : rJ0)*STRB;
    const int aPx = PXBASE + g*PXG + (g ? rJ0 : i0)*PXROW;
    const int loPx= PXBASE + g*PXG + (g ? rJm : i0)*PXROW;
    const int hiPx= PXBASE + g*PXG + (g ? rJ0 : i1)*PXROW + 88;  // fc1 +32 stays in-row
    const int sO  = myd*256 + i0*ODS;

    const bool act0 = wact && (ch     < mtiles);
    const bool act1 = wact && (ch + 2 < mtiles);
    const bool act2 = wact && (ch + 4 < mtiles);

    // loads for one tile into a staging slot
    auto LOAD = [&](int u, f16x8 bx2[2], f16x8 by2[2], u32x2& pA, u32x2& pB){
      const int du = u*TSTP;
      int vX = aX - du + plX; vX = imax(vX, loX);
      int vY = aY + du + plY; vY = imin(vY, hiY);
      bx2[0] = ld_state(smemc + vX);
      bx2[1] = ld_state(smemc + vX + 64);
      by2[0] = ld_state(smemc + vY);
      by2[1] = ld_state(smemc + vY + 64);
      if (dep == 0){
        int vp = aPx + (g ? -du : du) + plPx;
        vp = imin(imax(vp, loPx), hiPx);
        pA = *(const u32x2*)(smemc + vp);
        pB = *(const u32x2*)(smemc + vp + 32);
      }
    };
    // compute one tile from its staged fragments
    auto COMPUTE = [&](int u, const f16x8 bx2[2], const f16x8 by2[2],
                       u32x2 pA, u32x2 pB){
      const int du = u*TSTP;
      f32x4 a0, a1;
      if (dep == 0){
        a0[0] = f16tof(pA[0] & 0xffffu); a0[1] = f16tof(pA[0] >> 16);
        a0[2] = f16tof(pA[1] & 0xffffu); a0[3] = f16tof(pA[1] >> 16);
        a1[0] = f16tof(pB[0] & 0xffffu); a1[1] = f16tof(pB[0] >> 16);
        a1[2] = f16tof(pB[1] & 0xffffu); a1[3] = f16tof(pB[1] >> 16);
      } else {
        a0 = bias4[0]; a1 = bias4[1];
      }
      #pragma unroll
      for (int kk = 0; kk < 2; ++kk){
        a0 = __builtin_amdgcn_mfma_f32_16x16x32_f16(
               __builtin_bit_cast(f16x8, whf[kk][0]), bx2[kk], a0, 0, 0, 0);
        a1 = __builtin_amdgcn_mfma_f32_16x16x32_f16(
               __builtin_bit_cast(f16x8, whf[kk][1]), bx2[kk], a1, 0, 0, 0);
      }
      #pragma unroll
      for (int kk = 0; kk < 2; ++kk){
        a0 = __builtin_amdgcn_mfma_f32_16x16x32_f16(
               __builtin_bit_cast(f16x8, whf[kk+2][0]), by2[kk], a0, 0, 0, 0);
        a1 = __builtin_amdgcn_mfma_f32_16x16x32_f16(
               __builtin_bit_cast(f16x8, whf[kk+2][1]), by2[kk], a1, 0, 0, 0);
      }
      if (dep == 1){   // depth-1 projection from dep0's prev-parity state
        int vP = aP + (g ? du : -du) + plP;
        vP = imin(imax(vP, loP), hiP);
        #pragma unroll
        for (int kk = 0; kk < 2; ++kk){
          f16x8 pv = ld_state(smemc + vP + kk*64);
          a0 = __builtin_amdgcn_mfma_f32_16x16x32_f16(
                 __builtin_bit_cast(f16x8, wif[kk][0]), pv, a0, 0, 0, 0);
          a1 = __builtin_amdgcn_mfma_f32_16x16x32_f16(
                 __builtin_bit_cast(f16x8, wif[kk][1]), pv, a1, 0, 0, 0);
        }
      }
      float h0 = fast_tanh(a0[0]), h1 = fast_tanh(a0[1]);
      float h2 = fast_tanh(a0[2]), h3 = fast_tanh(a0[3]);
      float h4 = fast_tanh(a1[0]), h5 = fast_tanh(a1[1]);
      float h6 = fast_tanh(a1[2]), h7 = fast_tanh(a1[3]);
      if (c < nc - u*16){
        const int vW = aW + (g ? du : -du) + plW;
        u32x2 hp0; hp0[0] = pack2f16(h0, h1); hp0[1] = pack2f16(h2, h3);
        u32x2 hp1; hp1[0] = pack2f16(h4, h5); hp1[1] = pack2f16(h6, h7);
        *(u32x2*)(smemc + vW) = hp0;
        *(u32x2*)(smemc + vW + 32) = hp1;
        char* oa = outb + (u32)(sO + u*(16*ODS) + plO);
        f32x4 ov0 = {h0, h1, h2, h3};
        f32x4 ov1 = {h4, h5, h6, h7};
        *(f32x4*)(oa) = ov0;
        *(f32x4*)(oa + 64) = ov1;
      }
    };

    // depth-1 pipelined tile schedule: loads of tile t+1 precede compute of t
    f16x8 xa[2], ya[2], xb[2], yb[2];
    u32x2 pAa, pBa, pAb, pBb;
    if (act0) LOAD(ch,     xa, ya, pAa, pBa);
    if (act1) LOAD(ch + 2, xb, yb, pAb, pBb);
    if (act0) COMPUTE(ch,     xa, ya, pAa, pBa);
    if (act2) LOAD(ch + 4, xa, ya, pAa, pBa);
    if (act1) COMPUTE(ch + 2, xb, yb, pAb, pBb);
    if (act2) COMPUTE(ch + 4, xa, ya, pAa, pBa);

    barrier_lds_only();   // single barrier per round (parity buffers)
  }
}

extern "C" void kernel_launch(void* const* d_in, const int* in_sizes, int n_in,
                              void* d_out, int out_size, void* d_ws, size_t ws_size,
                              hipStream_t stream) {
  (void)in_sizes; (void)n_in; (void)ws_size;
  (void)hipFuncSetAttribute((const void*)grid_rnn_fused,
                            hipFuncAttributeMaxDynamicSharedMemorySize, LDSB);
  // invalid region (i>=sl or j>=tl) must read as exact zeros; kernel only
  // writes the valid sub-grid.
  (void)hipMemsetAsync(d_out, 0, (size_t)out_size, stream);
  proj0_kernel<<<dim3(Sn, 2, Bn), 64, 0, stream>>>(
      (const float*)d_in[0], (const float*)d_in[1],
      (const float*)d_in[2], (const float*)d_in[5],
      (const float*)d_in[4], (const float*)d_in[7],
      (float*)d_ws);
  grid_rnn_fused<<<dim3(Bn), dim3(1024), LDSB, stream>>>(
      (const float*)d_in[3], (const float*)d_in[6],
      (const float*)d_in[2], (const float*)d_in[5],
      (const float*)d_in[4], (const float*)d_in[7],
      (const int*)d_in[8], (const int*)d_in[9],
      (float*)d_out, (const float*)d_ws);
}

// Round 10
// 452.059 us; speedup vs baseline: 1.1103x; 1.1103x over previous
//
#include <hip/hip_runtime.h>

typedef unsigned short u16;
typedef unsigned int   u32;
typedef _Float16 f16x8 __attribute__((ext_vector_type(8)));
typedef float  f32x2  __attribute__((ext_vector_type(2)));
typedef float  f32x4  __attribute__((ext_vector_type(4)));
typedef int    i32x4  __attribute__((ext_vector_type(4)));
typedef u32    u32x2  __attribute__((ext_vector_type(2)));

#define Bn 8
#define Sn 96
#define Tn 96
#define Hn 64
#define H2n 128
#define STRB 152           // state row stride BYTES (128 used): conflict-free, 8B-aligned
#define ARRB 16384         // padded array stride -> scalar parity fold
#define STATEB 131072      // 8 state arrays (2dep x 2stream x 2parity)
#define PXROW 152          // px row stride bytes (128 used)
#define PXG   (Sn*PXROW)   // 14592
#define PXBASE STATEB
#define LDSB  (STATEB + 2*PXG)   // 160256 <= 163840
#define ODS 24320          // 95*Hn*4 : out byte stride per cell along a diagonal
#define TSTP 2432          // 16*STRB == 16*PXROW : byte step per 16-cell tile
#define TSCL 2.885390082f  // 2*log2(e): prescale so tanh needs no input mul

__device__ __forceinline__ int imax(int a, int b){ return a > b ? a : b; }
__device__ __forceinline__ int imin(int a, int b){ return a < b ? a : b; }

__device__ __forceinline__ u32 pack2f16(float a, float b){
  _Float16 ha = (_Float16)a, hb = (_Float16)b;    // v_cvt_f16_f32 (RNE)
  return (u32)__builtin_bit_cast(u16, ha) | ((u32)__builtin_bit_cast(u16, hb) << 16);
}
__device__ __forceinline__ float f16tof(u32 v){
  return (float)__builtin_bit_cast(_Float16, (u16)v);
}
// tanh with PRESCALED input z' = 2*log2(e)*z (scale folded into weights/bias/
// px at load): tanh = 1 - 2/(2^z' + 1). exp2 over/underflow saturates -> no
// clamp. 4 ops: exp2, add, rcp, fma (the mul moved off the serial chain).
__device__ __forceinline__ float fast_tanh_ps(float zp){
  float e = exp2f(zp);
  return __builtin_fmaf(-2.f, __builtin_amdgcn_rcpf(e + 1.f), 1.f);
}
// Workgroup barrier WITHOUT the vmcnt(0) drain __syncthreads() emits:
// only LDS ordering is needed between rounds (out is write-only, never read).
__device__ __forceinline__ void barrier_lds_only(){
  asm volatile("s_waitcnt vmcnt(63) expcnt(7) lgkmcnt(0)\n\ts_barrier" ::: "memory");
}
// state fragment: 8 f16 (16B) as two b64 reads (8B-aligned at STRB=152).
// NEVER use a b128 load here: at stride 152 it is misaligned for odd lanes
// and HW splits it on the dependency chain (R6: 3x regression).
__device__ __forceinline__ f16x8 ld_state(const char* p){
  u32x2 a = *(const u32x2*)(p);
  u32x2 b = *(const u32x2*)(p + 8);
  i32x4 v; v[0] = (int)a[0]; v[1] = (int)a[1]; v[2] = (int)b[0]; v[3] = (int)b[1];
  return __builtin_bit_cast(f16x8, v);
}

// Prologue: depth-0 input projections + bias, PRESCALED by TSCL, into ws.
__global__ __launch_bounds__(64) void proj0_kernel(
  const float* __restrict__ src, const float* __restrict__ trg,
  const float* __restrict__ Wix, const float* __restrict__ Wiy,
  const float* __restrict__ bx, const float* __restrict__ by,
  float* __restrict__ ws)
{
  const int row = blockIdx.x, g = blockIdx.y, b = blockIdx.z;
  const int n = threadIdx.x;
  const float* x = (g == 0) ? (src + (b*Sn + row)*Hn) : (trg + (b*Tn + row)*Hn);
  const float* W = (g == 0) ? Wix : Wiy;
  float a = (g == 0) ? bx[n] : by[n];
  #pragma unroll 8
  for (int f = 0; f < Hn; ++f) a = fmaf(x[f], W[f*Hn + n], a);
  ws[((size_t)(b*2 + g)*Sn + row)*Hn + n] = a * TSCL;
}

// Fused lag-1 wavefront, 1024 threads = 16 waves: wave = (g, ch, nh, dep).
// R8 structure (best verified 363us): 32 feats/wave (two 16-feat chunks
// SHARING every state B-fragment -> halved LDS redundancy), half the cell
// tiles each (u = ch, ch+2, ch+4), straight per-tile loop (R9's software
// pipeline regressed -> reverted). 16x16x32 MFMA; direct scattered out
// stores (absorbed by vmcnt(63), never on the round chain); single barrier
// per round; parity-double-buffered fp16 state at STRB=152 (conflict-free,
// 8B-aligned paired-b64 reads).
// R10: all z-contributors (Wh/Wi frags, bias, px) prescaled by 2*log2(e)
// at load -> tanh loses its input mul (serial-chain tail shortened).
// Valid-region only (rounds = sl+tl, diagonals clipped); invalid region
// pre-zeroed by memset. Clamped dead lanes read in-bounds finite LDS;
// their columns are never stored.
__global__ __launch_bounds__(1024, 1) void grid_rnn_fused(
  const float* __restrict__ Whx, const float* __restrict__ Why,
  const float* __restrict__ Wix, const float* __restrict__ Wiy,
  const float* __restrict__ bx,  const float* __restrict__ by,
  const int* __restrict__ src_lens, const int* __restrict__ trg_lens,
  float* __restrict__ out, const float* __restrict__ ws)
{
  extern __shared__ u16 smem[];
  char* const smemc = (char*)smem;
  const int b    = blockIdx.x;
  const int tid  = threadIdx.x;
  const int lane = tid & 63;
  const int wid  = __builtin_amdgcn_readfirstlane(tid >> 6);
  const int q    = lane >> 4;
  const int c    = lane & 15;
  const int dep  = wid & 1;
  const int nh   = (wid >> 1) & 1;   // feature half (32 feats)
  const int ch   = (wid >> 2) & 1;   // cell-tile parity
  const int g    = wid >> 3;
  const int sl = __builtin_amdgcn_readfirstlane(src_lens[b]);
  const int tl = __builtin_amdgcn_readfirstlane(trg_lens[b]);
  const int NB = sl + tl;

  for (int idx = tid; idx < STATEB/16; idx += 1024) ((i32x4*)smem)[idx] = (i32x4)(0);

  // stage px (already prescaled): ws fp32 -> LDS fp16 (row stride 152B)
  {
    const int gp = tid >> 9;          // 0/1 stream
    const int t5 = tid & 511;
    const float* wsg = ws + (size_t)(b*2 + gp)*Sn*Hn;
    #pragma unroll
    for (int it = 0; it < 6; ++it){
      int w = t5 + it*512;            // pair index 0..3071
      int row = w >> 5, pr = w & 31;
      f32x2 v = *(const f32x2*)(wsg + row*64 + pr*2);
      *(u32*)(smemc + PXBASE + gp*PXG + row*PXROW + pr*4) = pack2f16(v[0], v[1]);
    }
  }

  // ---- weights (own depth, own 32-feature half = 2 chunks), fp16 A-frags,
  // PRESCALED by TSCL
  const float* Wh = (g == 0 ? Whx : Why) + dep*H2n*Hn;
  i32x4 whf[4][2];
  #pragma unroll
  for (int kk = 0; kk < 4; ++kk)
    #pragma unroll
    for (int fc = 0; fc < 2; ++fc){
      const int nb = nh*32 + fc*16 + c;
      #pragma unroll
      for (int p = 0; p < 4; ++p){
        float w0 = Wh[(kk*32 + q*8 + 2*p    )*Hn + nb] * TSCL;
        float w1 = Wh[(kk*32 + q*8 + 2*p + 1)*Hn + nb] * TSCL;
        whf[kk][fc][p] = (int)pack2f16(w0, w1);
      }
    }
  const float* Wi = (g == 0 ? Wix : Wiy) + Hn*Hn;  // depth-1 slice (dep1 only)
  i32x4 wif[2][2];
  #pragma unroll
  for (int kk = 0; kk < 2; ++kk)
    #pragma unroll
    for (int fc = 0; fc < 2; ++fc){
      const int nb = nh*32 + fc*16 + c;
      #pragma unroll
      for (int p = 0; p < 4; ++p){
        float w0 = Wi[(kk*32 + q*8 + 2*p    )*Hn + nb] * TSCL;
        float w1 = Wi[(kk*32 + q*8 + 2*p + 1)*Hn + nb] * TSCL;
        wif[kk][fc][p] = (int)pack2f16(w0, w1);
      }
    }
  f32x4 bias4[2];  // depth-1 bias, prescaled (dep0 gets bias via ws)
  {
    const float* bb = (g == 0 ? bx : by) + dep*Hn;
    #pragma unroll
    for (int fc = 0; fc < 2; ++fc)
      #pragma unroll
      for (int r4 = 0; r4 < 4; ++r4)
        bias4[fc][r4] = bb[nh*32 + fc*16 + q*4 + r4] * TSCL;
  }
  char* const outb = (char*)(out + (size_t)((g*2 + dep)*Bn + b)*(size_t)(Sn*Tn)*Hn);

  // per-lane address parts (bytes)
  const int plX  = q*16 - c*STRB;                   // X reads: row j decreasing
  const int plY  = q*16 + c*STRB;                   // Y reads: row i increasing
  const int plP  = g ? plY : plX;
  const int plW  = (g ? c*STRB : -c*STRB) + nh*64 + q*8;   // fc1 at +32
  const int plPx = (g ? -c*PXROW : c*PXROW) + nh*64 + q*8; // fc1 at +32
  const int plO  = c*ODS + nh*128 + q*16;                  // fc1 at +64

  const int depB   = dep*4*ARRB;                    // [X p0][X p1][Y p0][Y p1]
  const int basePg = g ? 2*ARRB : 0;                // dep0's X / Y pair
  const int baseWg = depB + (g ? 2*ARRB : 0);

  __syncthreads();   // init + staging visible

  for (int r = 0; r < NB; ++r){
    const int myd  = r - dep;
    const bool wact = (myd >= 0) && (myd <= NB - 2);
    const int cpB = (r & 1) ? ARRB : 0;
    const int ppB = ARRB - cpB;
    const int i0 = imax(0, myd - (tl - 1));
    const int i1 = imin(sl - 1, myd);
    const int nc = i1 - i0 + 1;
    const int mtiles = (nc + 15) >> 4;
    const int rJ0 = myd - i0, rJm = myd - i1;
    const int aX  = depB + ppB + rJ0*STRB;
    const int loX = depB + ppB + rJm*STRB;
    const int aY  = depB + 2*ARRB + ppB + i0*STRB;
    const int hiY = depB + 2*ARRB + ppB + i1*STRB + 48;
    const int aP  = basePg + ppB + (g ? i0 : rJ0)*STRB;
    const int loP = basePg + ppB + (g ? i0 : rJm)*STRB;
    const int hiP = basePg + ppB + (g ? i1 : rJ0)*STRB + 48;
    const int aW  = baseWg + cpB + (g ? i0 : rJ0)*STRB;
    const int aPx = PXBASE + g*PXG + (g ? rJ0 : i0)*PXROW;
    const int loPx= PXBASE + g*PXG + (g ? rJm : i0)*PXROW;
    const int hiPx= PXBASE + g*PXG + (g ? rJ0 : i1)*PXROW + 88;  // fc1 +32 in-row
    const int sO  = myd*256 + i0*ODS;

    #pragma unroll
    for (int t = 0; t < 3; ++t){
      const int u = ch + 2*t;
      if (!(wact && u < mtiles)) continue;   // scalar branch
      const int du = u*TSTP;

      int vX = aX - du + plX; vX = imax(vX, loX);
      int vY = aY + du + plY; vY = imin(vY, hiY);

      // stage B fragments (shared by both feature chunks)
      f16x8 bvx[2], bvy[2];
      #pragma unroll
      for (int kk = 0; kk < 2; ++kk) bvx[kk] = ld_state(smemc + vX + kk*64);
      #pragma unroll
      for (int kk = 0; kk < 2; ++kk) bvy[kk] = ld_state(smemc + vY + kk*64);

      f32x4 a0, a1;
      if (dep == 0){
        int vp = aPx + (g ? -du : du) + plPx;
        vp = imin(imax(vp, loPx), hiPx);
        u32x2 p0 = *(const u32x2*)(smemc + vp);
        u32x2 p1 = *(const u32x2*)(smemc + vp + 32);
        a0[0] = f16tof(p0[0] & 0xffffu); a0[1] = f16tof(p0[0] >> 16);
        a0[2] = f16tof(p0[1] & 0xffffu); a0[3] = f16tof(p0[1] >> 16);
        a1[0] = f16tof(p1[0] & 0xffffu); a1[1] = f16tof(p1[0] >> 16);
        a1[2] = f16tof(p1[1] & 0xffffu); a1[3] = f16tof(p1[1] >> 16);
      } else {
        a0 = bias4[0]; a1 = bias4[1];
      }
      // recurrence K=128: kk 0-1 X (hx from col j), kk 2-3 Y (hy from row i)
      #pragma unroll
      for (int kk = 0; kk < 2; ++kk){
        a0 = __builtin_amdgcn_mfma_f32_16x16x32_f16(
               __builtin_bit_cast(f16x8, whf[kk][0]), bvx[kk], a0, 0, 0, 0);
        a1 = __builtin_amdgcn_mfma_f32_16x16x32_f16(
               __builtin_bit_cast(f16x8, whf[kk][1]), bvx[kk], a1, 0, 0, 0);
      }
      #pragma unroll
      for (int kk = 0; kk < 2; ++kk){
        a0 = __builtin_amdgcn_mfma_f32_16x16x32_f16(
               __builtin_bit_cast(f16x8, whf[kk+2][0]), bvy[kk], a0, 0, 0, 0);
        a1 = __builtin_amdgcn_mfma_f32_16x16x32_f16(
               __builtin_bit_cast(f16x8, whf[kk+2][1]), bvy[kk], a1, 0, 0, 0);
      }
      // depth-1 projection: dep0's h(i,j) from its previous-parity state slot
      if (dep == 1){
        int vP = aP + (g ? du : -du) + plP;
        vP = imin(imax(vP, loP), hiP);
        #pragma unroll
        for (int kk = 0; kk < 2; ++kk){
          f16x8 pv = ld_state(smemc + vP + kk*64);
          a0 = __builtin_amdgcn_mfma_f32_16x16x32_f16(
                 __builtin_bit_cast(f16x8, wif[kk][0]), pv, a0, 0, 0, 0);
          a1 = __builtin_amdgcn_mfma_f32_16x16x32_f16(
                 __builtin_bit_cast(f16x8, wif[kk][1]), pv, a1, 0, 0, 0);
        }
      }
      // tanh (prescaled input) -> state write (fp16, current parity) + out
      float h0 = fast_tanh_ps(a0[0]), h1 = fast_tanh_ps(a0[1]);
      float h2 = fast_tanh_ps(a0[2]), h3 = fast_tanh_ps(a0[3]);
      float h4 = fast_tanh_ps(a1[0]), h5 = fast_tanh_ps(a1[1]);
      float h6 = fast_tanh_ps(a1[2]), h7 = fast_tanh_ps(a1[3]);
      if (c < nc - u*16){
        const int vW = aW + (g ? du : -du) + plW;
        u32x2 hp0; hp0[0] = pack2f16(h0, h1); hp0[1] = pack2f16(h2, h3);
        u32x2 hp1; hp1[0] = pack2f16(h4, h5); hp1[1] = pack2f16(h6, h7);
        *(u32x2*)(smemc + vW) = hp0;
        *(u32x2*)(smemc + vW + 32) = hp1;
        char* oa = outb + (u32)(sO + u*(16*ODS) + plO);
        f32x4 ov0 = {h0, h1, h2, h3};
        f32x4 ov1 = {h4, h5, h6, h7};
        *(f32x4*)(oa) = ov0;
        *(f32x4*)(oa + 64) = ov1;
      }
    }
    barrier_lds_only();   // single barrier per round (parity buffers)
  }
}

extern "C" void kernel_launch(void* const* d_in, const int* in_sizes, int n_in,
                              void* d_out, int out_size, void* d_ws, size_t ws_size,
                              hipStream_t stream) {
  (void)in_sizes; (void)n_in; (void)ws_size;
  (void)hipFuncSetAttribute((const void*)grid_rnn_fused,
                            hipFuncAttributeMaxDynamicSharedMemorySize, LDSB);
  // invalid region (i>=sl or j>=tl) must read as exact zeros; kernel only
  // writes the valid sub-grid.
  (void)hipMemsetAsync(d_out, 0, (size_t)out_size, stream);
  proj0_kernel<<<dim3(Sn, 2, Bn), 64, 0, stream>>>(
      (const float*)d_in[0], (const float*)d_in[1],
      (const float*)d_in[2], (const float*)d_in[5],
      (const float*)d_in[4], (const float*)d_in[7],
      (float*)d_ws);
  grid_rnn_fused<<<dim3(Bn), dim3(1024), LDSB, stream>>>(
      (const float*)d_in[3], (const float*)d_in[6],
      (const float*)d_in[2], (const float*)d_in[5],
      (const float*)d_in[4], (const float*)d_in[7],
      (const int*)d_in[8], (const int*)d_in[9],
      (float*)d_out, (const float*)d_ws);
}